// Round 3
// baseline (246.224 us; speedup 1.0000x reference)
//
#include <hip/hip_runtime.h>
#include <stdint.h>

#define MAX_ITERS 20
#define EPSV 1e-7f
#define CLIPV 1e-7f
#define PI_F 3.14159265358979f
#define PIO2_F 1.57079632679490f

typedef __attribute__((ext_vector_type(8))) short short8;
typedef __attribute__((ext_vector_type(4))) float f4;

__device__ __forceinline__ f4 mfma_bf16(short8 a, short8 b, f4 c) {
    return __builtin_amdgcn_mfma_f32_16x16x32_bf16(a, b, c, 0, 0, 0);
}

__device__ __forceinline__ float rl(float v, int l) {
    return __int_as_float(__builtin_amdgcn_readlane(__float_as_int(v), l));
}

template <int CTRL>
__device__ __forceinline__ float dpp_add(float v) {
    int p = __builtin_amdgcn_update_dpp(0, __float_as_int(v), CTRL, 0xF, 0xF, true);
    return v + __int_as_float(p);
}
template <int CTRL>
__device__ __forceinline__ float dpp_mov(float v) {
    return __int_as_float(__builtin_amdgcn_update_dpp(0, __float_as_int(v), CTRL, 0xF, 0xF, true));
}

__device__ __forceinline__ float rowsum16(float v) {
    v = dpp_add<0xB1>(v);   // xor1
    v = dpp_add<0x4E>(v);   // xor2
    v = dpp_add<0x141>(v);  // xor4
    v = dpp_add<0x140>(v);  // xor8
    return v;
}

__device__ __forceinline__ float halfsum_rl(float v, bool hB) {
    v = rowsum16(v);
    float sA = rl(v, 0) + rl(v, 16);
    float sB = rl(v, 32) + rl(v, 48);
    return hB ? sB : sA;
}

__device__ __forceinline__ float halfsum_sw(float v) {
    v = rowsum16(v);
    int sw = __builtin_amdgcn_ds_swizzle(__float_as_int(v), 0x401F);  // xor16
    return v + __int_as_float(sw);
}

__device__ __forceinline__ float fast_acos(float x) {
    float a = fabsf(x);
    bool big = a > 0.5f;
    float z = big ? 0.5f * (1.0f - a) : x * x;
    float s = big ? sqrtf(z) : x;
    float p = fmaf(z, fmaf(z, fmaf(z, fmaf(z, 4.2163199048e-2f, 2.4181311049e-2f),
                                   4.5470025998e-2f), 7.4953002686e-2f),
                   1.6666752422e-1f);
    float r = fmaf(s * z, p, s);
    float big_val = (x < 0.0f) ? (PI_F - 2.0f * r) : (2.0f * r);
    return big ? big_val : (PIO2_F - r);
}

__device__ __forceinline__ void cvt_hilo(const float* v, short8& hi, short8& lo) {
#pragma unroll
    for (int i = 0; i < 8; ++i) {
        float x = v[i];
        uint32_t u = __float_as_uint(x);
        float hf = __uint_as_float(u & 0xFFFF0000u);
        float lf = x - hf;
        hi[i] = (short)(u >> 16);
        lo[i] = (short)(__float_as_uint(lf) >> 16);
    }
}

#define WSTEPA(CTRL, GI) { curA = dpp_mov<CTRL>(curA); accA = fmaf(Grow2[GI], curA, accA); }
#define WSTEPB(CTRL, GI) { curB = dpp_mov<CTRL>(curB); accB = fmaf(Grow2[(GI) + 16], curB, accB); }

// ============================================================================
// Kernel A: Gram + normalize + xor-permute, 1 group/wave, barrier-free.
// Writes Grow2 rows to gro[g*1024 + r*32 + j], fp32, coalesced.
// ============================================================================
__global__ void __launch_bounds__(256, 6) gram_norm(const float* __restrict__ X,
                                                    float* __restrict__ gro,
                                                    int n_groups) {
    __shared__ float sG[4][32 * 33];
    __shared__ float sInv[4][32];

    const int lane = threadIdx.x & 63;
    const int wid  = threadIdx.x >> 6;
    const int g    = blockIdx.x * 4 + wid;
    if (g >= n_groups) return;   // 8000 % 4 == 0: never diverges

    const float* Xg = X + (size_t)g * (32 * 128);
    const int col  = lane & 15;
    const int quad = lane >> 4;

    f4 acc00 = {0.f, 0.f, 0.f, 0.f};
    f4 acc01 = acc00, acc10 = acc00, acc11 = acc00;
#pragma unroll
    for (int kc = 0; kc < 4; ++kc) {
        const float* p0 = Xg + col * 128 + kc * 32 + quad * 8;
        const float* p1 = p0 + 16 * 128;
        float r0[8], r1[8];
        *(float4*)(r0)     = *(const float4*)(p0);
        *(float4*)(r0 + 4) = *(const float4*)(p0 + 4);
        *(float4*)(r1)     = *(const float4*)(p1);
        *(float4*)(r1 + 4) = *(const float4*)(p1 + 4);
        short8 H0, L0, H1, L1;
        cvt_hilo(r0, H0, L0);
        cvt_hilo(r1, H1, L1);
        acc00 = mfma_bf16(H0, H0, acc00);
        acc00 = mfma_bf16(H0, L0, acc00);
        acc00 = mfma_bf16(L0, H0, acc00);
        acc01 = mfma_bf16(H0, H1, acc01);
        acc01 = mfma_bf16(H0, L1, acc01);
        acc01 = mfma_bf16(L0, H1, acc01);
        acc10 = mfma_bf16(H1, H0, acc10);
        acc10 = mfma_bf16(H1, L0, acc10);
        acc10 = mfma_bf16(L1, H0, acc10);
        acc11 = mfma_bf16(H1, H1, acc11);
        acc11 = mfma_bf16(H1, L1, acc11);
        acc11 = mfma_bf16(L1, H1, acc11);
    }

    float* Gw = sG[wid];
#pragma unroll
    for (int i = 0; i < 4; ++i) {   // C/D: col=lane&15, row=quad*4+i (G sym)
        int rw = quad * 4 + i;
        Gw[rw * 33 + col]             = acc00[i];
        Gw[rw * 33 + col + 16]        = acc01[i];
        Gw[(rw + 16) * 33 + col]      = acc10[i];
        Gw[(rw + 16) * 33 + col + 16] = acc11[i];
    }
    // Tile is wave-private: no __syncthreads needed (within-wave LDS RAW is
    // ordered by lgkmcnt, which the compiler inserts).

    const int half = lane >> 5;
    const int r    = lane & 31;
    float inv = 1.0f / fmaxf(sqrtf(Gw[r * 34]), 1e-12f);   // diag r*33+r
    if (lane < 32) sInv[wid][r] = inv;   // halves duplicate: one writer

    float Grow2[32];
#pragma unroll
    for (int gg = 0; gg < 32; ++gg) {
        int j = r ^ gg;
        Grow2[gg] = Gw[r * 33 + j] * (inv * sInv[wid][j]);
    }

    float* dst = gro + (size_t)g * 1024 + r * 32;
    if (half == 0) {
        float4 t0 = {Grow2[0],  Grow2[1],  Grow2[2],  Grow2[3]};
        float4 t1 = {Grow2[4],  Grow2[5],  Grow2[6],  Grow2[7]};
        float4 t2 = {Grow2[8],  Grow2[9],  Grow2[10], Grow2[11]};
        float4 t3 = {Grow2[12], Grow2[13], Grow2[14], Grow2[15]};
        *(float4*)(dst + 0)  = t0;
        *(float4*)(dst + 4)  = t1;
        *(float4*)(dst + 8)  = t2;
        *(float4*)(dst + 12) = t3;
    } else {
        float4 t0 = {Grow2[16], Grow2[17], Grow2[18], Grow2[19]};
        float4 t1 = {Grow2[20], Grow2[21], Grow2[22], Grow2[23]};
        float4 t2 = {Grow2[24], Grow2[25], Grow2[26], Grow2[27]};
        float4 t3 = {Grow2[28], Grow2[29], Grow2[30], Grow2[31]};
        *(float4*)(dst + 16) = t0;
        *(float4*)(dst + 20) = t1;
        *(float4*)(dst + 24) = t2;
        *(float4*)(dst + 28) = t3;
    }
}

// ============================================================================
// Kernel B: Karcher iterations in Gram space. 1 wave/block, 2 groups/wave.
// Reads coalesced fp32 G-rows (L3-hot). Pure-VALU loop, 2 DS swizzles/iter.
// ============================================================================
__global__ void __launch_bounds__(64) iterate(const float* __restrict__ gro,
                                              float* __restrict__ part,
                                              int n_groups) {
    const int  lane = threadIdx.x;
    const int  half = lane >> 5;
    const bool hB   = half != 0;
    const int  r    = lane & 31;
    const int  g0   = blockIdx.x * 2;
    if (g0 >= n_groups) return;   // 8000 % 2 == 0

    const float* src = gro + (size_t)(g0 + half) * 1024 + r * 32;
    float Grow2[32];
#pragma unroll
    for (int t = 0; t < 8; ++t) {
        float4 v = *(const float4*)(src + t * 4);
        Grow2[t * 4 + 0] = v.x;
        Grow2[t * 4 + 1] = v.y;
        Grow2[t * 4 + 2] = v.z;
        Grow2[t * 4 + 3] = v.w;
    }

    // ---- mu0 = normalize(mean(Xn)) in coefficient space ----
    float a = 1.0f / 32.0f;
    float ga;
    {
        float s0 = 0, s1 = 0, s2 = 0, s3 = 0;
#pragma unroll
        for (int g = 0; g < 8; ++g) {
            s0 += Grow2[g];
            s1 += Grow2[g + 8];
            s2 += Grow2[g + 16];
            s3 += Grow2[g + 24];
        }
        ga = ((s0 + s1) + (s2 + s3)) * (1.0f / 32.0f);
        float n2   = halfsum_rl(a * ga, hB);
        float inv0 = 1.0f / fmaxf(sqrtf(n2), 1e-12f);
        a  *= inv0;
        ga *= inv0;
    }

    // ---- Karcher iterations, Gray-code DPP matvec ----
    for (int it = 0; it < MAX_ITERS; ++it) {
        float x  = fminf(fmaxf(ga, -1.0f + CLIPV), 1.0f - CLIPV);
        float th = fast_acos(x);
        float st = fmaxf(sqrtf(fmaxf(1.0f - x * x, 0.0f)), EPSV);
        float w  = __fdividef(th, st);

        int w16i = __builtin_amdgcn_ds_swizzle(__float_as_int(w), 0x401F);
        float C = halfsum_sw(w * ga);

        float curA = w;
        float accA = Grow2[0] * curA;
        WSTEPA(0xB1, 1)   WSTEPA(0x4E, 3)   WSTEPA(0xB1, 2)   WSTEPA(0x141, 6)
        WSTEPA(0xB1, 7)   WSTEPA(0x4E, 5)   WSTEPA(0xB1, 4)   WSTEPA(0x140, 12)
        WSTEPA(0xB1, 13)  WSTEPA(0x4E, 15)  WSTEPA(0xB1, 14)  WSTEPA(0x141, 10)
        WSTEPA(0xB1, 11)  WSTEPA(0x4E, 9)   WSTEPA(0xB1, 8)

        float curB = __int_as_float(w16i);
        float accB = Grow2[16] * curB;
        WSTEPB(0xB1, 1)   WSTEPB(0x4E, 3)   WSTEPB(0xB1, 2)   WSTEPB(0x141, 6)
        WSTEPB(0xB1, 7)   WSTEPB(0x4E, 5)   WSTEPB(0xB1, 4)   WSTEPB(0x140, 12)
        WSTEPB(0xB1, 13)  WSTEPB(0x4E, 15)  WSTEPB(0xB1, 14)  WSTEPB(0x141, 10)
        WSTEPB(0xB1, 11)  WSTEPB(0x4E, 9)   WSTEPB(0xB1, 8)

        float gw   = accA + accB;
        float gb   = (gw - C * ga) * (1.0f / 32.0f);
        float beta = (w  - C * a ) * (1.0f / 32.0f);

        float vv = halfsum_rl(beta * gb, hB);
        float vs = fmaxf(sqrtf(fmaxf(vv, 0.0f)), EPSV);
        float cv = __cosf(vs);
        float sv = __fdividef(__sinf(vs), vs);
        a  = fmaf(sv, beta, cv * a);
        ga = fmaf(sv, gb, cv * ga);
        if (__all(vs < 1e-6f)) break;
    }

    float xf = fminf(fmaxf(ga, -1.0f + CLIPV), 1.0f - CLIPV);
    float t  = fast_acos(xf);
    float ls = halfsum_rl(t * t, hB);
    float total = rl(ls, 0) + rl(ls, 32);
    if (lane == 0) part[blockIdx.x] = total;
}

// ============================================================================
// Fallback: round-2 monolithic kernel (used only if ws is too small)
// ============================================================================
__global__ void __launch_bounds__(256, 4) karcher_mono(const float* __restrict__ X,
                                                       float* __restrict__ ws,
                                                       int n_groups) {
    __shared__ float sG[8][32 * 33];
    __shared__ float sInv[8][32];
    __shared__ float sPart[8];

    const int lane = threadIdx.x & 63;
    const int wid  = threadIdx.x >> 6;
    const int g0   = blockIdx.x * 8 + wid * 2;
    if (threadIdx.x < 8) sPart[threadIdx.x] = 0.f;
    if (g0 >= n_groups) return;

    const int col  = lane & 15;
    const int quad = lane >> 4;

#pragma unroll
    for (int gg = 0; gg < 2; ++gg) {
        if (g0 + gg >= n_groups) break;
        const float* Xg = X + (size_t)(g0 + gg) * (32 * 128);
        f4 acc00 = {0.f, 0.f, 0.f, 0.f};
        f4 acc01 = acc00, acc10 = acc00, acc11 = acc00;
#pragma unroll
        for (int kc = 0; kc < 4; ++kc) {
            const float* p0 = Xg + col * 128 + kc * 32 + quad * 8;
            const float* p1 = p0 + 16 * 128;
            float r0[8], r1[8];
            *(float4*)(r0)     = *(const float4*)(p0);
            *(float4*)(r0 + 4) = *(const float4*)(p0 + 4);
            *(float4*)(r1)     = *(const float4*)(p1);
            *(float4*)(r1 + 4) = *(const float4*)(p1 + 4);
            short8 H0, L0, H1, L1;
            cvt_hilo(r0, H0, L0);
            cvt_hilo(r1, H1, L1);
            acc00 = mfma_bf16(H0, H0, acc00);
            acc00 = mfma_bf16(H0, L0, acc00);
            acc00 = mfma_bf16(L0, H0, acc00);
            acc01 = mfma_bf16(H0, H1, acc01);
            acc01 = mfma_bf16(H0, L1, acc01);
            acc01 = mfma_bf16(L0, H1, acc01);
            acc10 = mfma_bf16(H1, H0, acc10);
            acc10 = mfma_bf16(H1, L0, acc10);
            acc10 = mfma_bf16(L1, H0, acc10);
            acc11 = mfma_bf16(H1, H1, acc11);
            acc11 = mfma_bf16(H1, L1, acc11);
            acc11 = mfma_bf16(L1, H1, acc11);
        }
        float* Gw = sG[wid * 2 + gg];
#pragma unroll
        for (int i = 0; i < 4; ++i) {
            int rw = quad * 4 + i;
            Gw[rw * 33 + col]             = acc00[i];
            Gw[rw * 33 + col + 16]        = acc01[i];
            Gw[(rw + 16) * 33 + col]      = acc10[i];
            Gw[(rw + 16) * 33 + col + 16] = acc11[i];
        }
    }
    __syncthreads();

    const int  half = lane >> 5;
    const bool hB   = half != 0;
    const int  r    = lane & 31;
    const float* Gh  = sG[wid * 2 + half];
    float*       siH = sInv[wid * 2 + half];

    float inv = 1.0f / fmaxf(sqrtf(Gh[r * 34]), 1e-12f);
    siH[r] = inv;
    __syncthreads();

    float Grow2[32];
#pragma unroll
    for (int g = 0; g < 32; ++g) {
        int j = r ^ g;
        Grow2[g] = Gh[r * 33 + j] * (inv * siH[j]);
    }

    float a = 1.0f / 32.0f;
    float ga;
    {
        float s0 = 0, s1 = 0, s2 = 0, s3 = 0;
#pragma unroll
        for (int g = 0; g < 8; ++g) {
            s0 += Grow2[g];
            s1 += Grow2[g + 8];
            s2 += Grow2[g + 16];
            s3 += Grow2[g + 24];
        }
        ga = ((s0 + s1) + (s2 + s3)) * (1.0f / 32.0f);
        float n2   = halfsum_rl(a * ga, hB);
        float inv0 = 1.0f / fmaxf(sqrtf(n2), 1e-12f);
        a  *= inv0;
        ga *= inv0;
    }

    for (int it = 0; it < MAX_ITERS; ++it) {
        float x  = fminf(fmaxf(ga, -1.0f + CLIPV), 1.0f - CLIPV);
        float th = fast_acos(x);
        float st = fmaxf(sqrtf(fmaxf(1.0f - x * x, 0.0f)), EPSV);
        float w  = __fdividef(th, st);
        int w16i = __builtin_amdgcn_ds_swizzle(__float_as_int(w), 0x401F);
        float C = halfsum_sw(w * ga);
        float curA = w;
        float accA = Grow2[0] * curA;
        WSTEPA(0xB1, 1)   WSTEPA(0x4E, 3)   WSTEPA(0xB1, 2)   WSTEPA(0x141, 6)
        WSTEPA(0xB1, 7)   WSTEPA(0x4E, 5)   WSTEPA(0xB1, 4)   WSTEPA(0x140, 12)
        WSTEPA(0xB1, 13)  WSTEPA(0x4E, 15)  WSTEPA(0xB1, 14)  WSTEPA(0x141, 10)
        WSTEPA(0xB1, 11)  WSTEPA(0x4E, 9)   WSTEPA(0xB1, 8)
        float curB = __int_as_float(w16i);
        float accB = Grow2[16] * curB;
        WSTEPB(0xB1, 1)   WSTEPB(0x4E, 3)   WSTEPB(0xB1, 2)   WSTEPB(0x141, 6)
        WSTEPB(0xB1, 7)   WSTEPB(0x4E, 5)   WSTEPB(0xB1, 4)   WSTEPB(0x140, 12)
        WSTEPB(0xB1, 13)  WSTEPB(0x4E, 15)  WSTEPB(0xB1, 14)  WSTEPB(0x141, 10)
        WSTEPB(0xB1, 11)  WSTEPB(0x4E, 9)   WSTEPB(0xB1, 8)
        float gw   = accA + accB;
        float gb   = (gw - C * ga) * (1.0f / 32.0f);
        float beta = (w  - C * a ) * (1.0f / 32.0f);
        float vv = halfsum_rl(beta * gb, hB);
        float vs = fmaxf(sqrtf(fmaxf(vv, 0.0f)), EPSV);
        float cv = __cosf(vs);
        float sv = __fdividef(__sinf(vs), vs);
        a  = fmaf(sv, beta, cv * a);
        ga = fmaf(sv, gb, cv * ga);
        if (__all(vs < 1e-6f)) break;
    }

    float xf = fminf(fmaxf(ga, -1.0f + CLIPV), 1.0f - CLIPV);
    float t  = fast_acos(xf);
    float ls = halfsum_rl(t * t, hB);
    if (r == 0 && (g0 + half) < n_groups) sPart[wid * 2 + half] = ls;
    __syncthreads();
    if (threadIdx.x == 0) {
        float s = 0.f;
#pragma unroll
        for (int i = 0; i < 8; ++i) s += sPart[i];
        ws[blockIdx.x] = s;
    }
}

__global__ void __launch_bounds__(256) reduce_partials(const float* __restrict__ ws,
                                                       float* __restrict__ out,
                                                       int n, float scale) {
    __shared__ float sred[4];
    float s = 0.f;
    for (int i = threadIdx.x; i < n; i += 256) s += ws[i];
#pragma unroll
    for (int m = 32; m >= 1; m >>= 1) s += __shfl_xor(s, m, 64);
    const int lane = threadIdx.x & 63, wid = threadIdx.x >> 6;
    if (lane == 0) sred[wid] = s;
    __syncthreads();
    if (threadIdx.x == 0)
        out[0] = ((sred[0] + sred[1]) + (sred[2] + sred[3])) * scale;
}

extern "C" void kernel_launch(void* const* d_in, const int* in_sizes, int n_in,
                              void* d_out, int out_size, void* d_ws, size_t ws_size,
                              hipStream_t stream) {
    const float* X = (const float*)d_in[0];
    float* out = (float*)d_out;
    float* ws = (float*)d_ws;
    int n_groups = in_sizes[0] / (32 * 128);   // 8000

    int blocksA = (n_groups + 3) / 4;          // 2000: 1 group/wave
    int blocksB = (n_groups + 1) / 2;          // 4000: 2 groups/wave, 1-wave blocks
    size_t need = (size_t)n_groups * 1024 * sizeof(float)
                + (size_t)blocksB * sizeof(float);

    if (ws_size >= need) {
        float* gro  = ws;                              // 32.8 MB G-rows
        float* part = ws + (size_t)n_groups * 1024;    // per-block partials
        gram_norm<<<blocksA, 256, 0, stream>>>(X, gro, n_groups);
        iterate<<<blocksB, 64, 0, stream>>>(gro, part, n_groups);
        reduce_partials<<<1, 256, 0, stream>>>(part, out, blocksB,
                                               1.0f / (float)n_groups);
    } else {
        int blocks = (n_groups + 7) / 8;       // 1000 blocks, 2 groups/wave
        karcher_mono<<<blocks, 256, 0, stream>>>(X, ws, n_groups);
        reduce_partials<<<1, 256, 0, stream>>>(ws, out, blocks,
                                               1.0f / (float)n_groups);
    }
}

// Round 4
// 217.234 us; speedup vs baseline: 1.1335x; 1.1335x over previous
//
#include <hip/hip_runtime.h>
#include <stdint.h>

#define MAX_ITERS 20
#define EPSV 1e-7f
#define CLIPV 1e-7f
#define PI_F 3.14159265358979f
#define PIO2_F 1.57079632679490f

typedef __attribute__((ext_vector_type(8))) short short8;
typedef __attribute__((ext_vector_type(4))) float f4;

__device__ __forceinline__ f4 mfma_bf16(short8 a, short8 b, f4 c) {
    return __builtin_amdgcn_mfma_f32_16x16x32_bf16(a, b, c, 0, 0, 0);
}

__device__ __forceinline__ float rl(float v, int l) {
    return __int_as_float(__builtin_amdgcn_readlane(__float_as_int(v), l));
}

template <int CTRL>
__device__ __forceinline__ float dpp_add(float v) {
    int p = __builtin_amdgcn_update_dpp(0, __float_as_int(v), CTRL, 0xF, 0xF, true);
    return v + __int_as_float(p);
}
template <int CTRL>
__device__ __forceinline__ float dpp_mov(float v) {
    return __int_as_float(__builtin_amdgcn_update_dpp(0, __float_as_int(v), CTRL, 0xF, 0xF, true));
}

__device__ __forceinline__ float rowsum16(float v) {
    v = dpp_add<0xB1>(v);   // xor1
    v = dpp_add<0x4E>(v);   // xor2
    v = dpp_add<0x141>(v);  // xor4
    v = dpp_add<0x140>(v);  // xor8
    return v;
}

// wave-uniform sum over 32 distinct values (halves duplicated)
__device__ __forceinline__ float wavesum32(float v) {
    v = rowsum16(v);
    return rl(v, 0) + rl(v, 16);
}

// sum over own 32-lane half via one ds_swizzle xor16 (latency-hidden use)
__device__ __forceinline__ float halfsum_sw(float v) {
    v = rowsum16(v);
    int sw = __builtin_amdgcn_ds_swizzle(__float_as_int(v), 0x401F);  // xor16
    return v + __int_as_float(sw);
}

__device__ __forceinline__ float fast_acos(float x) {
    float a = fabsf(x);
    bool big = a > 0.5f;
    float z = big ? 0.5f * (1.0f - a) : x * x;
    float s = big ? sqrtf(z) : x;
    float p = fmaf(z, fmaf(z, fmaf(z, fmaf(z, 4.2163199048e-2f, 2.4181311049e-2f),
                                   4.5470025998e-2f), 7.4953002686e-2f),
                   1.6666752422e-1f);
    float r = fmaf(s * z, p, s);
    float big_val = (x < 0.0f) ? (PI_F - 2.0f * r) : (2.0f * r);
    return big ? big_val : (PIO2_F - r);
}

__device__ __forceinline__ void cvt_hilo(const float* v, short8& hi, short8& lo) {
#pragma unroll
    for (int i = 0; i < 8; ++i) {
        float x = v[i];
        uint32_t u = __float_as_uint(x);
        float hf = __uint_as_float(u & 0xFFFF0000u);
        float lf = x - hf;
        hi[i] = (short)(u >> 16);
        lo[i] = (short)(__float_as_uint(lf) >> 16);
    }
}

#define WSTEPA(CTRL, GI) { curA = dpp_mov<CTRL>(curA); accA = fmaf(Grow2[GI], curA, accA); }
#define WSTEPB(CTRL, GI) { curB = dpp_mov<CTRL>(curB); accB = fmaf(Grow2[(GI) + 16], curB, accB); }

// async global->LDS, 16B per lane; dest = lds_ptr + lane*16 (HW), src per-lane
#define GLOAD_LDS16(srcp, ldsp)                                                   \
    __builtin_amdgcn_global_load_lds(                                             \
        (const __attribute__((address_space(1))) uint32_t*)(srcp),                \
        (__attribute__((address_space(3))) uint32_t*)(ldsp), 16, 0, 0)

// ============================================================================
// Monolithic: 4 groups/block (1 per wave). Coalesced async staging into LDS
// (pre-swizzled source so ds_read_b128 fragment reads are conflict-optimal),
// Gram via MFMA hi/lo bf16 split, Karcher loop in 32-dim Gram space (pure
// VALU Gray-code DPP matvec), per-block partial loss. Barrier-free except the
// final 4-way partial aggregation.
// ============================================================================
__global__ void __launch_bounds__(256) karcher(const float* __restrict__ X,
                                               float* __restrict__ ws,
                                               int n_groups) {
    __shared__ float stage[4][4096];   // 64 KB: per-wave 32x128 tile (swizzled)
    __shared__ float sInv[4][32];
    __shared__ float sPart[4];

    const int lane = threadIdx.x & 63;
    const int wid  = threadIdx.x >> 6;
    const int g    = blockIdx.x * 4 + wid;
    if (g >= n_groups) return;   // 8000 % 4 == 0: never diverges

    // ---- Phase 0: async coalesced staging, source pre-swizzled --------------
    // Tile granule (16B) coords: row rr (0..31), granule g2 (0..31).
    // LDS granule (rr, g2) receives X granule (rr, g2 ^ (rr&7))  [involution].
    // Dest granule of instr i, lane l: gi = i*64 + l -> rr = 2i + (l>>5),
    // g2 = l&31. Linear LDS dest = stage[wid] + i*1024B + lane*16B (HW rule).
    const float* Xg = X + (size_t)g * 4096;
    {
        const int g2  = lane & 31;
        const int rrb = lane >> 5;
#pragma unroll
        for (int i = 0; i < 16; ++i) {
            int rr  = 2 * i + rrb;
            int g2s = g2 ^ (rr & 7);
            const float* src = Xg + rr * 128 + g2s * 4;
            GLOAD_LDS16(src, &stage[wid][i * 256]);
        }
    }
    asm volatile("s_waitcnt vmcnt(0)" ::: "memory");
    __builtin_amdgcn_sched_barrier(0);
    // Tile is wave-private: no __syncthreads. ds_read ordering via lgkmcnt.

    const int col  = lane & 15;
    const int quad = lane >> 4;

    // ---- Phase 1: Gram = X X^T via MFMA, fragments from swizzled LDS --------
    f4 acc00 = {0.f, 0.f, 0.f, 0.f};
    f4 acc01 = acc00, acc10 = acc00, acc11 = acc00;
    {
        float* st = stage[wid];
        const int x0 = col & 7;          // (col&7) == ((col+16)&7)
        const int b0 = col * 128;
        const int b1 = (col + 16) * 128;
#pragma unroll
        for (int kc = 0; kc < 4; ++kc) {
            int s   = kc * 4 + quad;                 // 8-float slot index
            int ga0 = ((s * 2 + 0) ^ x0) * 4;        // swizzled granule offsets
            int ga1 = ((s * 2 + 1) ^ x0) * 4;
            float r0[8], r1[8];
            *(float4*)(r0)     = *(const float4*)(st + b0 + ga0);
            *(float4*)(r0 + 4) = *(const float4*)(st + b0 + ga1);
            *(float4*)(r1)     = *(const float4*)(st + b1 + ga0);
            *(float4*)(r1 + 4) = *(const float4*)(st + b1 + ga1);
            short8 H0, L0, H1, L1;
            cvt_hilo(r0, H0, L0);
            cvt_hilo(r1, H1, L1);
            acc00 = mfma_bf16(H0, H0, acc00);
            acc00 = mfma_bf16(H0, L0, acc00);
            acc00 = mfma_bf16(L0, H0, acc00);
            acc01 = mfma_bf16(H0, H1, acc01);
            acc01 = mfma_bf16(H0, L1, acc01);
            acc01 = mfma_bf16(L0, H1, acc01);
            acc10 = mfma_bf16(H1, H0, acc10);
            acc10 = mfma_bf16(H1, L0, acc10);
            acc10 = mfma_bf16(L1, H0, acc10);
            acc11 = mfma_bf16(H1, H1, acc11);
            acc11 = mfma_bf16(H1, L1, acc11);
            acc11 = mfma_bf16(L1, H1, acc11);
        }
    }

    // ---- Phase 2: write G into (dead) staging region, overlay ---------------
    float* Gw = stage[wid];   // staged X fully consumed by this wave: reuse
#pragma unroll
    for (int i = 0; i < 4; ++i) {   // C/D: col=lane&15, row=quad*4+i (G sym)
        int rw = quad * 4 + i;
        Gw[rw * 33 + col]             = acc00[i];
        Gw[rw * 33 + col + 16]        = acc01[i];
        Gw[(rw + 16) * 33 + col]      = acc10[i];
        Gw[(rw + 16) * 33 + col + 16] = acc11[i];
    }

    // ---- Phase 3: xor-permuted normalized Gram row into VGPRs ---------------
    const int r = lane & 31;
    float inv = 1.0f / fmaxf(sqrtf(Gw[r * 34]), 1e-12f);   // diag r*33+r
    if (lane < 32) sInv[wid][r] = inv;                     // halves duplicate

    float Grow2[32];
#pragma unroll
    for (int gg = 0; gg < 32; ++gg) {
        int j = r ^ gg;
        Grow2[gg] = Gw[r * 33 + j] * (inv * sInv[wid][j]);
    }

    // ---- Phase 4: mu0 = normalize(mean(Xn)) in coefficient space ------------
    float a = 1.0f / 32.0f;
    float ga;
    {
        float s0 = 0, s1 = 0, s2 = 0, s3 = 0;
#pragma unroll
        for (int gg = 0; gg < 8; ++gg) {
            s0 += Grow2[gg];
            s1 += Grow2[gg + 8];
            s2 += Grow2[gg + 16];
            s3 += Grow2[gg + 24];
        }
        ga = ((s0 + s1) + (s2 + s3)) * (1.0f / 32.0f);
        float n2   = wavesum32(a * ga);
        float inv0 = 1.0f / fmaxf(sqrtf(n2), 1e-12f);
        a  *= inv0;
        ga *= inv0;
    }

    // ---- Phase 5: Karcher iterations, Gray-code DPP matvec ------------------
    for (int it = 0; it < MAX_ITERS; ++it) {
        float x  = fminf(fmaxf(ga, -1.0f + CLIPV), 1.0f - CLIPV);
        float th = fast_acos(x);
        float st = fmaxf(sqrtf(fmaxf(1.0f - x * x, 0.0f)), EPSV);
        float w  = __fdividef(th, st);

        // xor16 seed for walk B; overlaps with walk A + C reduction
        int w16i = __builtin_amdgcn_ds_swizzle(__float_as_int(w), 0x401F);
        float C = halfsum_sw(w * ga);   // sum_n w_n dot_n (latency hidden)

        float curA = w;
        float accA = Grow2[0] * curA;
        WSTEPA(0xB1, 1)   WSTEPA(0x4E, 3)   WSTEPA(0xB1, 2)   WSTEPA(0x141, 6)
        WSTEPA(0xB1, 7)   WSTEPA(0x4E, 5)   WSTEPA(0xB1, 4)   WSTEPA(0x140, 12)
        WSTEPA(0xB1, 13)  WSTEPA(0x4E, 15)  WSTEPA(0xB1, 14)  WSTEPA(0x141, 10)
        WSTEPA(0xB1, 11)  WSTEPA(0x4E, 9)   WSTEPA(0xB1, 8)

        float curB = __int_as_float(w16i);
        float accB = Grow2[16] * curB;
        WSTEPB(0xB1, 1)   WSTEPB(0x4E, 3)   WSTEPB(0xB1, 2)   WSTEPB(0x141, 6)
        WSTEPB(0xB1, 7)   WSTEPB(0x4E, 5)   WSTEPB(0xB1, 4)   WSTEPB(0x140, 12)
        WSTEPB(0xB1, 13)  WSTEPB(0x4E, 15)  WSTEPB(0xB1, 14)  WSTEPB(0x141, 10)
        WSTEPB(0xB1, 11)  WSTEPB(0x4E, 9)   WSTEPB(0xB1, 8)

        float gw   = accA + accB;                  // (G w)_r
        float gb   = (gw - C * ga) * (1.0f / 32.0f);
        float beta = (w  - C * a ) * (1.0f / 32.0f);

        float vv = wavesum32(beta * gb);           // ||v||^2 = beta^T G beta
        float vs = fmaxf(sqrtf(fmaxf(vv, 0.0f)), EPSV);
        float cv = __cosf(vs);
        float sv = __fdividef(__sinf(vs), vs);
        a  = fmaf(sv, beta, cv * a);               // exp map (v perp mu)
        ga = fmaf(sv, gb, cv * ga);
        if (vs < 1e-6f) break;  // wave-uniform (1 group/wave)
    }

    // ---- Phase 6: per-block partial loss ------------------------------------
    float xf = fminf(fmaxf(ga, -1.0f + CLIPV), 1.0f - CLIPV);
    float t  = fast_acos(xf);
    float ls = wavesum32(t * t);   // wave-uniform
    if (lane == 0) sPart[wid] = ls;
    __syncthreads();
    if (threadIdx.x == 0)
        ws[blockIdx.x] = (sPart[0] + sPart[1]) + (sPart[2] + sPart[3]);
}

__global__ void __launch_bounds__(256) reduce_partials(const float* __restrict__ ws,
                                                       float* __restrict__ out,
                                                       int n, float scale) {
    __shared__ float sred[4];
    float s = 0.f;
    for (int i = threadIdx.x; i < n; i += 256) s += ws[i];
#pragma unroll
    for (int m = 32; m >= 1; m >>= 1) s += __shfl_xor(s, m, 64);
    const int lane = threadIdx.x & 63, wid = threadIdx.x >> 6;
    if (lane == 0) sred[wid] = s;
    __syncthreads();
    if (threadIdx.x == 0)
        out[0] = ((sred[0] + sred[1]) + (sred[2] + sred[3])) * scale;
}

extern "C" void kernel_launch(void* const* d_in, const int* in_sizes, int n_in,
                              void* d_out, int out_size, void* d_ws, size_t ws_size,
                              hipStream_t stream) {
    const float* X = (const float*)d_in[0];
    float* out = (float*)d_out;
    float* ws = (float*)d_ws;
    int n_groups = in_sizes[0] / (32 * 128);   // 8000
    int blocks = (n_groups + 3) / 4;           // 2000 blocks, 1 group/wave
    karcher<<<blocks, 256, 0, stream>>>(X, ws, n_groups);
    reduce_partials<<<1, 256, 0, stream>>>(ws, out, blocks, 1.0f / (float)n_groups);
}

// Round 5
// 211.090 us; speedup vs baseline: 1.1664x; 1.0291x over previous
//
#include <hip/hip_runtime.h>
#include <stdint.h>

#define MAX_ITERS 20
#define EPSV 1e-7f
#define CLIPV 1e-7f
#define PI_F 3.14159265358979f
#define PIO2_F 1.57079632679490f

typedef __attribute__((ext_vector_type(8))) short short8;
typedef __attribute__((ext_vector_type(4))) float f4;

__device__ __forceinline__ f4 mfma_bf16(short8 a, short8 b, f4 c) {
    return __builtin_amdgcn_mfma_f32_16x16x32_bf16(a, b, c, 0, 0, 0);
}

__device__ __forceinline__ float rl(float v, int l) {
    return __int_as_float(__builtin_amdgcn_readlane(__float_as_int(v), l));
}

template <int CTRL>
__device__ __forceinline__ float dpp_add(float v) {
    int p = __builtin_amdgcn_update_dpp(0, __float_as_int(v), CTRL, 0xF, 0xF, true);
    return v + __int_as_float(p);
}
template <int CTRL>
__device__ __forceinline__ float dpp_mov(float v) {
    return __int_as_float(__builtin_amdgcn_update_dpp(0, __float_as_int(v), CTRL, 0xF, 0xF, true));
}

__device__ __forceinline__ float rowsum16(float v) {
    v = dpp_add<0xB1>(v);   // xor1
    v = dpp_add<0x4E>(v);   // xor2
    v = dpp_add<0x141>(v);  // xor4
    v = dpp_add<0x140>(v);  // xor8
    return v;
}

// sum over own 32-lane half, result in all lanes of that half (readlane path)
__device__ __forceinline__ float halfsum_rl(float v, bool hB) {
    v = rowsum16(v);
    float sA = rl(v, 0) + rl(v, 16);
    float sB = rl(v, 32) + rl(v, 48);
    return hB ? sB : sA;
}

// sum over own 32-lane half via one ds_swizzle xor16 (latency-hidden use)
__device__ __forceinline__ float halfsum_sw(float v) {
    v = rowsum16(v);
    int sw = __builtin_amdgcn_ds_swizzle(__float_as_int(v), 0x401F);  // xor16
    return v + __int_as_float(sw);
}

__device__ __forceinline__ float fast_acos(float x) {
    float a = fabsf(x);
    bool big = a > 0.5f;
    float z = big ? 0.5f * (1.0f - a) : x * x;
    float s = big ? sqrtf(z) : x;
    float p = fmaf(z, fmaf(z, fmaf(z, fmaf(z, 4.2163199048e-2f, 2.4181311049e-2f),
                                   4.5470025998e-2f), 7.4953002686e-2f),
                   1.6666752422e-1f);
    float r = fmaf(s * z, p, s);
    float big_val = (x < 0.0f) ? (PI_F - 2.0f * r) : (2.0f * r);
    return big ? big_val : (PIO2_F - r);
}

__device__ __forceinline__ void cvt_hilo(const float* v, short8& hi, short8& lo) {
#pragma unroll
    for (int i = 0; i < 8; ++i) {
        float x = v[i];
        uint32_t u = __float_as_uint(x);
        float hf = __uint_as_float(u & 0xFFFF0000u);
        float lf = x - hf;
        hi[i] = (short)(u >> 16);
        lo[i] = (short)(__float_as_uint(lf) >> 16);
    }
}

#define WSTEPA(CTRL, GI) { curA = dpp_mov<CTRL>(curA); accA = fmaf(Grow2[GI], curA, accA); }
#define WSTEPB(CTRL, GI) { curB = dpp_mov<CTRL>(curB); accB = fmaf(Grow2[(GI) + 16], curB, accB); }

// async global->LDS, 16B per lane; LDS dest = ldsp + lane*16 (HW rule)
#define GLOAD_LDS16(srcp, ldsp)                                                   \
    __builtin_amdgcn_global_load_lds(                                             \
        (const __attribute__((address_space(1))) uint32_t*)(srcp),                \
        (__attribute__((address_space(3))) uint32_t*)(ldsp), 16, 0, 0)

// swizzled G element address (floats), 32x32 tile, granule-XOR on (row&7)
__device__ __forceinline__ int gidx(int row, int j) {
    return row * 32 + ((((j >> 2) ^ (row & 7)) << 2) | (j & 3));
}

// ============================================================================
// 8 groups/block, 2 per wave (lanes 0-31 own g0, lanes 32-63 own g0+1).
// Per wave: 8 KB LDS = two 4-KB slots. Each group's Gram accumulates over
// four 32x32-float K-quarters staged coalesced via global_load_lds with a
// granule-XOR swizzle (linear dest + pre-swizzled source + swizzled read).
// G0 overlays slot A, G1 slot B once their tiles are consumed. Karcher loop
// is the round-2 verified Gray-code DPP matvec (pure VALU, 2 DS ops/iter).
// ============================================================================
__global__ void __launch_bounds__(256, 4) karcher(const float* __restrict__ X,
                                                  float* __restrict__ ws,
                                                  int n_groups) {
    __shared__ float lds[4][2048];   // per-wave: slotA [0,1024) | slotB [1024,2048)
    __shared__ float sInv[4][64];
    __shared__ float sPart[8];

    const int lane = threadIdx.x & 63;
    const int wid  = threadIdx.x >> 6;
    const int g0   = blockIdx.x * 8 + wid * 2;
    if (g0 >= n_groups) return;   // 8000 % 8 == 0: never diverges

    const int col  = lane & 15;
    const int quad = lane >> 4;

    float* slotA = lds[wid];
    float* slotB = lds[wid] + 1024;

    // stage one 32x32-float K-quarter, coalesced, source pre-swizzled.
    // granule (16B) gi = i*64 + lane -> row rr = gi>>3, slot-granule g2 = gi&7;
    // LDS granule (rr,g2) receives X granule (rr, g2 ^ (rr&7))  [involution]
    const int rrl = lane >> 3;   // 0..7
    const int g2l = lane & 7;
    auto stage = [&](const float* Xg, int kq, float* slot) {
#pragma unroll
        for (int i = 0; i < 4; ++i) {
            int rr  = i * 8 + rrl;
            int g2s = g2l ^ (rr & 7);
            GLOAD_LDS16(Xg + rr * 128 + kq * 32 + g2s * 4, slot + i * 256);
        }
    };

    // accumulate one K-quarter into the Gram accs from a staged (swizzled) tile
    const int x0 = col & 7;
    const int b0 = col * 32;
    const int b1 = (col + 16) * 32;
    f4 a00 = {0.f, 0.f, 0.f, 0.f}, a01 = a00, a10 = a00, a11 = a00;
    auto gramq = [&](const float* st) {
        int s0 = ((quad * 2 + 0) ^ x0) * 4;
        int s1 = ((quad * 2 + 1) ^ x0) * 4;
        float r0[8], r1[8];
        *(float4*)(r0)     = *(const float4*)(st + b0 + s0);
        *(float4*)(r0 + 4) = *(const float4*)(st + b0 + s1);
        *(float4*)(r1)     = *(const float4*)(st + b1 + s0);
        *(float4*)(r1 + 4) = *(const float4*)(st + b1 + s1);
        short8 H0, L0, H1, L1;
        cvt_hilo(r0, H0, L0);
        cvt_hilo(r1, H1, L1);
        a00 = mfma_bf16(H0, H0, a00);
        a00 = mfma_bf16(H0, L0, a00);
        a00 = mfma_bf16(L0, H0, a00);
        a01 = mfma_bf16(H0, H1, a01);
        a01 = mfma_bf16(H0, L1, a01);
        a01 = mfma_bf16(L0, H1, a01);
        a10 = mfma_bf16(H1, H0, a10);
        a10 = mfma_bf16(H1, L0, a10);
        a10 = mfma_bf16(L1, H0, a10);
        a11 = mfma_bf16(H1, H1, a11);
        a11 = mfma_bf16(H1, L1, a11);
        a11 = mfma_bf16(L1, H1, a11);
    };

    // write accumulated G (32x32, granule-XOR swizzled) into a slot
    auto writeG = [&](float* Gs) {
#pragma unroll
        for (int i = 0; i < 4; ++i) {   // C/D: col=lane&15, row=quad*4+i (G sym)
            int rw = quad * 4 + i;
            Gs[gidx(rw,      col)]      = a00[i];
            Gs[gidx(rw,      col + 16)] = a01[i];
            Gs[gidx(rw + 16, col)]      = a10[i];
            Gs[gidx(rw + 16, col + 16)] = a11[i];
        }
    };

#define WAIT_VM0() do {                                   \
        asm volatile("s_waitcnt vmcnt(0)" ::: "memory");  \
        __builtin_amdgcn_sched_barrier(0);                \
    } while (0)

    // ---- group 0: 4 quarters, A/B alternating (both slots free) -------------
    {
        const float* Xg = X + (size_t)g0 * 4096;
        stage(Xg, 0, slotA);
        WAIT_VM0();
        gramq(slotA);
        stage(Xg, 1, slotB);
        WAIT_VM0();
        gramq(slotB);
        stage(Xg, 2, slotA);
        WAIT_VM0();
        gramq(slotA);
        stage(Xg, 3, slotB);
        WAIT_VM0();
        gramq(slotB);
        writeG(slotA);   // G0 -> slot A (tile fully consumed)
    }
    // ---- group 1: 4 quarters through slot B (A holds G0) --------------------
    {
        const float* Xg = X + (size_t)(g0 + 1) * 4096;
        a00 = {0.f, 0.f, 0.f, 0.f}; a01 = a00; a10 = a00; a11 = a00;
        stage(Xg, 0, slotB);
        WAIT_VM0();
        gramq(slotB);
        stage(Xg, 1, slotB);
        WAIT_VM0();
        gramq(slotB);
        stage(Xg, 2, slotB);
        WAIT_VM0();
        gramq(slotB);
        stage(Xg, 3, slotB);
        WAIT_VM0();
        gramq(slotB);
        writeG(slotB);   // G1 -> slot B
    }

    // ---- Phase 3: xor-permuted normalized Gram row into VGPRs ---------------
    const int  half = lane >> 5;
    const bool hB   = half != 0;
    const int  r    = lane & 31;
    const float* Gh = lds[wid] + half * 1024;

    float inv = 1.0f / fmaxf(sqrtf(Gh[gidx(r, r)]), 1e-12f);
    sInv[wid][lane] = inv;                 // 64 entries: [half*32 + r]
    const float* sI = sInv[wid] + half * 32;

    float Grow2[32];
#pragma unroll
    for (int gg = 0; gg < 32; ++gg) {
        int j = r ^ gg;
        Grow2[gg] = Gh[gidx(r, j)] * (inv * sI[j]);
    }

    // ---- Phase 4: mu0 = normalize(mean(Xn)) in coefficient space ------------
    float a = 1.0f / 32.0f;
    float ga;
    {
        float s0 = 0, s1 = 0, s2 = 0, s3 = 0;
#pragma unroll
        for (int gg = 0; gg < 8; ++gg) {
            s0 += Grow2[gg];
            s1 += Grow2[gg + 8];
            s2 += Grow2[gg + 16];
            s3 += Grow2[gg + 24];
        }
        ga = ((s0 + s1) + (s2 + s3)) * (1.0f / 32.0f);
        float n2   = halfsum_rl(a * ga, hB);
        float inv0 = 1.0f / fmaxf(sqrtf(n2), 1e-12f);
        a  *= inv0;
        ga *= inv0;
    }

    // ---- Phase 5: Karcher iterations, Gray-code DPP matvec ------------------
    for (int it = 0; it < MAX_ITERS; ++it) {
        float x  = fminf(fmaxf(ga, -1.0f + CLIPV), 1.0f - CLIPV);
        float th = fast_acos(x);
        float st = fmaxf(sqrtf(fmaxf(1.0f - x * x, 0.0f)), EPSV);
        float w  = __fdividef(th, st);

        // xor16 seed for walk B; overlaps with walk A + C reduction
        int w16i = __builtin_amdgcn_ds_swizzle(__float_as_int(w), 0x401F);
        float C = halfsum_sw(w * ga);   // sum_n w_n dot_n (latency hidden)

        float curA = w;
        float accA = Grow2[0] * curA;
        WSTEPA(0xB1, 1)   WSTEPA(0x4E, 3)   WSTEPA(0xB1, 2)   WSTEPA(0x141, 6)
        WSTEPA(0xB1, 7)   WSTEPA(0x4E, 5)   WSTEPA(0xB1, 4)   WSTEPA(0x140, 12)
        WSTEPA(0xB1, 13)  WSTEPA(0x4E, 15)  WSTEPA(0xB1, 14)  WSTEPA(0x141, 10)
        WSTEPA(0xB1, 11)  WSTEPA(0x4E, 9)   WSTEPA(0xB1, 8)

        float curB = __int_as_float(w16i);
        float accB = Grow2[16] * curB;
        WSTEPB(0xB1, 1)   WSTEPB(0x4E, 3)   WSTEPB(0xB1, 2)   WSTEPB(0x141, 6)
        WSTEPB(0xB1, 7)   WSTEPB(0x4E, 5)   WSTEPB(0xB1, 4)   WSTEPB(0x140, 12)
        WSTEPB(0xB1, 13)  WSTEPB(0x4E, 15)  WSTEPB(0xB1, 14)  WSTEPB(0x141, 10)
        WSTEPB(0xB1, 11)  WSTEPB(0x4E, 9)   WSTEPB(0xB1, 8)

        float gw   = accA + accB;                  // (G w)_r
        float gb   = (gw - C * ga) * (1.0f / 32.0f);
        float beta = (w  - C * a ) * (1.0f / 32.0f);

        float vv = halfsum_rl(beta * gb, hB);      // ||v||^2 = beta^T G beta
        float vs = fmaxf(sqrtf(fmaxf(vv, 0.0f)), EPSV);
        float cv = __cosf(vs);
        float sv = __fdividef(__sinf(vs), vs);
        a  = fmaf(sv, beta, cv * a);               // exp map (v perp mu)
        ga = fmaf(sv, gb, cv * ga);
        if (__all(vs < 1e-6f)) break;  // both halves converged
    }

    // ---- Phase 6: per-block partial loss ------------------------------------
    float xf = fminf(fmaxf(ga, -1.0f + CLIPV), 1.0f - CLIPV);
    float t  = fast_acos(xf);
    float ls = halfsum_rl(t * t, hB);   // per-half uniform
    if (r == 0) sPart[wid * 2 + half] = ls;
    __syncthreads();
    if (threadIdx.x == 0) {
        float s = 0.f;
#pragma unroll
        for (int i = 0; i < 8; ++i) s += sPart[i];
        ws[blockIdx.x] = s;
    }
}

__global__ void __launch_bounds__(256) reduce_partials(const float* __restrict__ ws,
                                                       float* __restrict__ out,
                                                       int n, float scale) {
    __shared__ float sred[4];
    float s = 0.f;
    for (int i = threadIdx.x; i < n; i += 256) s += ws[i];
#pragma unroll
    for (int m = 32; m >= 1; m >>= 1) s += __shfl_xor(s, m, 64);
    const int lane = threadIdx.x & 63, wid = threadIdx.x >> 6;
    if (lane == 0) sred[wid] = s;
    __syncthreads();
    if (threadIdx.x == 0)
        out[0] = ((sred[0] + sred[1]) + (sred[2] + sred[3])) * scale;
}

extern "C" void kernel_launch(void* const* d_in, const int* in_sizes, int n_in,
                              void* d_out, int out_size, void* d_ws, size_t ws_size,
                              hipStream_t stream) {
    const float* X = (const float*)d_in[0];
    float* out = (float*)d_out;
    float* ws = (float*)d_ws;
    int n_groups = in_sizes[0] / (32 * 128);   // 8000
    int blocks = (n_groups + 7) / 8;           // 1000 blocks, 2 groups/wave
    karcher<<<blocks, 256, 0, stream>>>(X, ws, n_groups);
    reduce_partials<<<1, 256, 0, stream>>>(ws, out, blocks, 1.0f / (float)n_groups);
}